// Round 13
// baseline (3943.921 us; speedup 1.0000x reference)
//
#include <hip/hip_runtime.h>
#include <cstdint>
#include <cstddef>

#define V_SZ 32000
#define H_SZ 1024
#define T_SZ 512
#define B_SZ 64

typedef short short8 __attribute__((ext_vector_type(8)));
typedef float f32x4 __attribute__((ext_vector_type(4)));
typedef unsigned long long u64;

__device__ __forceinline__ short f2bf(float f) {
  union { float f; unsigned u; } v; v.f = f;
  unsigned r = (v.u + 0x7fffu + ((v.u >> 16) & 1u)) >> 16;  // RNE, inputs finite
  return (short)r;
}

__device__ __forceinline__ unsigned cvtpk(float a, float b) {  // lo=bf16(a), hi=bf16(b)
  unsigned r;
  asm("v_cvt_pk_bf16_f32 %0, %1, %2" : "=v"(r) : "v"(a), "v"(b));
  return r;
}

__device__ __forceinline__ float fsig(float x) {   // 1/(1+e^-x) via v_exp/v_rcp
  return __builtin_amdgcn_rcpf(1.f + __builtin_amdgcn_exp2f(x * -1.44269504f));
}
__device__ __forceinline__ float ftanh(float x) {  // 1 - 2/(e^2x+1)
  return 1.f - 2.f * __builtin_amdgcn_rcpf(1.f + __builtin_amdgcn_exp2f(x * 2.88539008f));
}

// embT[v][h] = bf16(emb_w[h][v] + emb_b[h])  -- tiled transpose, both sides coalesced
__global__ __launch_bounds__(256) void k_embT(const float* __restrict__ emb_w,
                                              const float* __restrict__ emb_b,
                                              short* __restrict__ embT) {
  __shared__ float tile[64][65];
  const int v0 = blockIdx.x * 64, h0 = blockIdx.y * 64;
  const int c = threadIdx.x & 63, rg = threadIdx.x >> 6;
#pragma unroll
  for (int p = 0; p < 16; ++p) {
    int r = rg * 16 + p;
    tile[r][c] = emb_w[(size_t)(h0 + r) * V_SZ + v0 + c];
  }
  __syncthreads();
  const float bias = emb_b[h0 + c];
#pragma unroll
  for (int p = 0; p < 16; ++p) {
    int vr = rg * 16 + p;
    embT[(size_t)(v0 + vr) * H_SZ + h0 + c] = f2bf(tile[c][vr] + bias);
  }
}

__global__ __launch_bounds__(256) void k_cast(const float* __restrict__ s,
                                              short* __restrict__ d, int n) {
  for (int i = blockIdx.x * 256 + threadIdx.x; i < n; i += gridDim.x * 256)
    d[i] = f2bf(s[i]);
}

__global__ __launch_bounds__(256) void k_copy(const float* __restrict__ s,
                                              float* __restrict__ d, int n) {
  for (int i = blockIdx.x * 256 + threadIdx.x; i < n; i += gridDim.x * 256)
    d[i] = s[i];
}

// Persistent bidirectional LSTM. 256 blocks x 512 threads, 1 block/CU.
// block: d = bid>>7, bg = (bid&127)>>6, cg = bid&63, n0 = cg*16.
// h-exchange THROUGH out[] hidden (write-once f32): producer publishes via UC
// 16B write-through stores (drain + per-wave flag); consumer polls its 64
// producer-wave flags then reads h(t-1) with PLAIN CACHED 16B loads -> the
// 64x read reuse is served by XCD L2 (UC 16 MB/step fabric traffic -> ~2 MB
// L3 + L2 hits). cvt_pk f32->bf16 in-register (same rounding as before).
// One-time entry __threadfence() drops poisoned lines (validated round 10).
// Weights (Bf[8][4]=128 regs) in registers all 512 steps; c-state in register.
__global__ __launch_bounds__(512, 2) void k_persist(
    const int* __restrict__ tokens, const short* __restrict__ embT,
    const short* __restrict__ Wbf, const float* __restrict__ biasws,
    unsigned* __restrict__ bar, float* __restrict__ out) {
  __shared__ float P_lds[8][32][68];   // [K-eighth][b32][64 cols + 4 pad]

  const int tid = threadIdx.x;
  const int lane = tid & 63, w = tid >> 6;
  const int l15 = lane & 15, l4 = lane >> 4;
  const int d = (int)(blockIdx.x >> 7);
  const int bflat = (int)(blockIdx.x & 127);
  const int bg = bflat >> 6;                 // batch half
  const int cg = bflat & 63;                 // col group
  const int n0 = cg << 4;
  const int r0 = bg * 32 + l15, r1 = r0 + 16;  // A-fragment batch rows
  const int kw = w * 32 + l4 * 8;              // lane k-base

  __threadfence();  // one-time: invalidate poisoned out[] lines in this XCD's L1/L2

  // ---- step-invariant B fragments in registers: chunk w+jj*8, N-tile nt ----
  short8 Bf[8][4];
#pragma unroll
  for (int jj = 0; jj < 8; ++jj) {
    int slab = w + jj * 8;
#pragma unroll
    for (int nt = 0; nt < 4; ++nt) {
      int row64 = nt * 16 + l15;             // flat (gate,col) 0..63
      size_t grow = (size_t)((d * 4 + (row64 >> 4)) * 1024 + n0 + (row64 & 15));
      Bf[jj][nt] = *(const short8*)(Wbf + grow * 2048 + slab * 32 + l4 * 8);
    }
  }

  // ---- gate-phase constants: thread owns (b32=tid>>4, c16=tid&15) ----
  const int b32 = tid >> 4, c16 = tid & 15;
  const int gcol = n0 + c16, gbrow = bg * 32 + b32;
  float brg[4];
#pragma unroll
  for (int g4 = 0; g4 < 4; ++g4) brg[g4] = biasws[d * 4096 + g4 * 1024 + gcol];
  float c_reg = 0.f;

  // ---- dataflow flags: u32 [d][bg][cg][wave]; monotone, no reset ----
  unsigned* const grpf = bar + (d * 2 + bg) * 512;
  unsigned* const fpub = grpf + cg * 8 + w;          // this wave's own flag
  unsigned* const fpoll =                            // lane -> (q,i,wp) flag
      grpf + ((lane >> 4) * 16 + 2 * w + ((lane >> 3) & 1)) * 8 + (lane & 7);

  const f32x4 fzero = {0.f, 0.f, 0.f, 0.f};
  f32x4 acc[2][4];

  // x-half of step s (token-dependent only): cached direct-to-frag + 32 MFMA.
  auto X_PHASE = [&](int s) {
    const int td = d ? (T_SZ - 1 - s) : s;
    const short* xb0 = embT + (size_t)tokens[td * B_SZ + r0] * 1024 + kw;
    const short* xb1 = embT + (size_t)tokens[td * B_SZ + r1] * 1024 + kw;
    short8 xf[2][4];
#pragma unroll
    for (int jj = 0; jj < 4; ++jj) {         // chunk w+jj*8 -> +jj*256 elements
      xf[0][jj] = *(const short8*)(xb0 + jj * 256);
      xf[1][jj] = *(const short8*)(xb1 + jj * 256);
    }
#pragma unroll
    for (int ms = 0; ms < 2; ++ms)
#pragma unroll
      for (int nt = 0; nt < 4; ++nt) acc[ms][nt] = fzero;
#pragma unroll
    for (int jj = 0; jj < 4; ++jj)
#pragma unroll
      for (int ms = 0; ms < 2; ++ms)
#pragma unroll
        for (int nt = 0; nt < 4; ++nt)
          acc[ms][nt] = __builtin_amdgcn_mfma_f32_16x16x32_bf16(
              xf[ms][jj], Bf[jj][nt], acc[ms][nt], 0, 0, 0);
  };

  X_PHASE(0);  // prologue

  for (int t = 0; t < T_SZ; ++t) {
    if (t > 0) {
      // ---- per-wave poll: my 8 producers' 8 wave-flags >= t ----
      const unsigned tgt = (unsigned)t;
      while (true) {
        unsigned v = __hip_atomic_load(fpoll, __ATOMIC_RELAXED,
                                       __HIP_MEMORY_SCOPE_AGENT);
        if (__all(v >= tgt)) break;
        __builtin_amdgcn_s_sleep(1);
      }
      // ---- h-half: CACHED f32 16B loads of out[t-1] + cvt_pk -> bf16 frags ----
      const float* hb0 = out + ((size_t)(t - 1) * B_SZ + r0) * 2048 + (size_t)d * 1024 + kw;
      const float* hb1 = out + ((size_t)(t - 1) * B_SZ + r1) * 2048 + (size_t)d * 1024 + kw;
      f32x4 a[4][2], b[4][2];
#pragma unroll
      for (int q = 0; q < 4; ++q) {          // issue all loads first (MLP)
        a[q][0] = *(const f32x4*)(hb0 + q * 256);
        a[q][1] = *(const f32x4*)(hb0 + q * 256 + 4);
        b[q][0] = *(const f32x4*)(hb1 + q * 256);
        b[q][1] = *(const f32x4*)(hb1 + q * 256 + 4);
      }
      short8 hf[2][4];
#pragma unroll
      for (int q = 0; q < 4; ++q) {
        union { unsigned u[4]; short8 s; } c0, c1;
        c0.u[0] = cvtpk(a[q][0][0], a[q][0][1]); c0.u[1] = cvtpk(a[q][0][2], a[q][0][3]);
        c0.u[2] = cvtpk(a[q][1][0], a[q][1][1]); c0.u[3] = cvtpk(a[q][1][2], a[q][1][3]);
        c1.u[0] = cvtpk(b[q][0][0], b[q][0][1]); c1.u[1] = cvtpk(b[q][0][2], b[q][0][3]);
        c1.u[2] = cvtpk(b[q][1][0], b[q][1][1]); c1.u[3] = cvtpk(b[q][1][2], b[q][1][3]);
        hf[0][q] = c0.s; hf[1][q] = c1.s;
      }
#pragma unroll
      for (int q = 0; q < 4; ++q)
#pragma unroll
        for (int ms = 0; ms < 2; ++ms)
#pragma unroll
          for (int nt = 0; nt < 4; ++nt)
            acc[ms][nt] = __builtin_amdgcn_mfma_f32_16x16x32_bf16(
                hf[ms][q], Bf[4 + q][nt], acc[ms][nt], 0, 0, 0);
    }

    // ---- K-split partial dump (C layout: row=l4*4+i, col=l15) ----
#pragma unroll
    for (int ms = 0; ms < 2; ++ms)
#pragma unroll
      for (int nt = 0; nt < 4; ++nt)
#pragma unroll
        for (int i = 0; i < 4; ++i)
          P_lds[w][ms * 16 + l4 * 4 + i][nt * 16 + l15] = acc[ms][nt][i];
    __syncthreads();  // S1

    // ---- gate math + state update (thread: b32, c16) ----
    float pr[4];
#pragma unroll
    for (int g4 = 0; g4 < 4; ++g4) {
      float s = brg[g4];
#pragma unroll
      for (int q = 0; q < 8; ++q) s += P_lds[q][b32][g4 * 16 + c16];
      pr[g4] = s;
    }
    float ig = fsig(pr[0]);
    float og = fsig(pr[1]);
    float fg = fsig(pr[2]);
    float cg4 = ftanh(pr[3]);
    c_reg = fg * c_reg + ig * cg4;
    float hnew = og * ftanh(c_reg);

    // ---- publish hidden to out[]: shuffle-pack 4 f32 -> one 16B UC store ----
    {
      float s1 = __shfl_down(hnew, 1);
      float s2 = __shfl_down(hnew, 2);
      float s3 = __shfl_down(hnew, 3);
      if ((lane & 3) == 0) {
        f32x4 pk = {hnew, s1, s2, s3};
        float* p = out + ((size_t)t * B_SZ + bg * 32 + (w * 4 + (lane >> 4))) * 2048 +
                   (size_t)d * 1024 + n0 + (lane & 15);
        asm volatile("global_store_dwordx4 %0, %1, off sc0 sc1"
                     :: "v"(p), "v"(pk) : "memory");
      }
    }
    if (t < T_SZ - 1) {
      asm volatile("s_waitcnt vmcnt(0)" ::: "memory");  // publish visible in L3
      if (lane == 0)
        __hip_atomic_store(fpub, (unsigned)(t + 1), __ATOMIC_RELAXED,
                           __HIP_MEMORY_SCOPE_AGENT);
    }

    // cell store (plain cached, off critical path)
    out[(size_t)(t * B_SZ + gbrow) * 2048 + (size_t)d * 1024 + gcol + 67108864] = c_reg;

    __syncthreads();  // S2: all gate reads of P_lds done -> next dump safe
    if (t < T_SZ - 1) X_PHASE(t + 1);  // overlap flag propagation + h-latency
  }
}

extern "C" void kernel_launch(void* const* d_in, const int* in_sizes, int n_in,
                              void* d_out, int out_size, void* d_ws, size_t ws_size,
                              hipStream_t stream) {
  (void)in_sizes; (void)n_in; (void)out_size; (void)ws_size;
  const int* tokens  = (const int*)d_in[0];
  const float* emb_w = (const float*)d_in[1];
  const float* emb_b = (const float*)d_in[2];

  char* ws = (char*)d_ws;
  short* embT   = (short*)(ws);               // 65,536,000 B
  short* Wbf    = (short*)(ws + 65536000);    // 33,554,432 B
  float* biasws = (float*)(ws + 99090432);    //     32,768 B
  unsigned* bar = (unsigned*)(ws + 99123200); //      8,192 B (per-wave flags)

  (void)hipMemsetAsync(ws + 99123200, 0, 8192, stream);

  k_embT<<<dim3(500, 16), 256, 0, stream>>>(emb_w, emb_b, embT);

  for (int d = 0; d < 2; ++d)
    for (int g = 0; g < 4; ++g) {
      const float* wsrc = (const float*)d_in[3 + d * 8 + g * 2];
      const float* bsrc = (const float*)d_in[4 + d * 8 + g * 2];
      k_cast<<<1024, 256, 0, stream>>>(wsrc, Wbf + (size_t)(d * 4 + g) * 1024 * 2048,
                                       1024 * 2048);
      k_copy<<<4, 256, 0, stream>>>(bsrc, biasws + (d * 4 + g) * 1024, 1024);
    }

  float* outp = (float*)d_out;
  void* kargs[] = {(void*)&tokens, (void*)&embT, (void*)&Wbf, (void*)&biasws,
                   (void*)&bar, (void*)&outp};
  (void)hipLaunchCooperativeKernel((const void*)k_persist, dim3(256), dim3(512), kargs,
                                   0, stream);
}

// Round 14
// 3234.739 us; speedup vs baseline: 1.2192x; 1.2192x over previous
//
#include <hip/hip_runtime.h>
#include <cstdint>
#include <cstddef>

#define V_SZ 32000
#define H_SZ 1024
#define T_SZ 512
#define B_SZ 64

typedef short short8 __attribute__((ext_vector_type(8)));
typedef float f32x4 __attribute__((ext_vector_type(4)));
typedef unsigned long long u64;

__device__ __forceinline__ short f2bf(float f) {
  union { float f; unsigned u; } v; v.f = f;
  unsigned r = (v.u + 0x7fffu + ((v.u >> 16) & 1u)) >> 16;  // RNE, inputs finite
  return (short)r;
}

__device__ __forceinline__ unsigned cvtpk(float a, float b) {  // lo=bf16(a), hi=bf16(b)
  unsigned r;
  asm("v_cvt_pk_bf16_f32 %0, %1, %2" : "=v"(r) : "v"(a), "v"(b));
  return r;
}

__device__ __forceinline__ float fsig(float x) {
  return __builtin_amdgcn_rcpf(1.f + __builtin_amdgcn_exp2f(x * -1.44269504f));
}
__device__ __forceinline__ float ftanh(float x) {
  return 1.f - 2.f * __builtin_amdgcn_rcpf(1.f + __builtin_amdgcn_exp2f(x * 2.88539008f));
}

__global__ __launch_bounds__(256) void k_embT(const float* __restrict__ emb_w,
                                              const float* __restrict__ emb_b,
                                              short* __restrict__ embT) {
  __shared__ float tile[64][65];
  const int v0 = blockIdx.x * 64, h0 = blockIdx.y * 64;
  const int c = threadIdx.x & 63, rg = threadIdx.x >> 6;
#pragma unroll
  for (int p = 0; p < 16; ++p) {
    int r = rg * 16 + p;
    tile[r][c] = emb_w[(size_t)(h0 + r) * V_SZ + v0 + c];
  }
  __syncthreads();
  const float bias = emb_b[h0 + c];
#pragma unroll
  for (int p = 0; p < 16; ++p) {
    int vr = rg * 16 + p;
    embT[(size_t)(v0 + vr) * H_SZ + h0 + c] = f2bf(tile[c][vr] + bias);
  }
}

__global__ __launch_bounds__(256) void k_cast(const float* __restrict__ s,
                                              short* __restrict__ d, int n) {
  for (int i = blockIdx.x * 256 + threadIdx.x; i < n; i += gridDim.x * 256)
    d[i] = f2bf(s[i]);
}

__global__ __launch_bounds__(256) void k_copy(const float* __restrict__ s,
                                              float* __restrict__ d, int n) {
  for (int i = blockIdx.x * 256 + threadIdx.x; i < n; i += gridDim.x * 256)
    d[i] = s[i];
}

// Persistent bidirectional LSTM. 256 blocks x 512 threads, 1 block/CU.
// CACHED=1: h-exchange via write-once bf16 hseq[t][d][64][1024] -- producers
//   UC-store (L3-visible), consumers PLAIN cached loads (first touch per XCD
//   from L3, then L2-served 8x reuse; write-once per dispatch => never stale;
//   validated mechanism in round 13). 8x fewer fabric requests than UC reads.
// CACHED=0: 2-phase UC bf16 hbf (round-12 path).
// Both: ping-pong P_lds -> ONE barrier per step; per-wave 16B publish + flag;
// per-wave poll of the 64 producer-wave flags it actually consumes.
// Safety (both): publish(t+1) happens after S1(t), which joins all 8 waves'
// polls(t); their producer-set union = all 64 blocks x 8 waves at flag(t),
// each implying that block passed S1(t-1) (all its reads(t-1) done).
template <bool CACHED>
__global__ __launch_bounds__(512, 2) void k_persist(
    const int* __restrict__ tokens, const short* __restrict__ embT,
    const short* __restrict__ Wbf, const float* __restrict__ biasws,
    short* __restrict__ hbf, short* __restrict__ hseq,
    unsigned* __restrict__ bar, float* __restrict__ out) {
  __shared__ float P_lds[2][8][32][68];  // ping-pong [K-eighth][b32][64+4 pad]

  const int tid = threadIdx.x;
  const int lane = tid & 63, w = tid >> 6;
  const int l15 = lane & 15, l4 = lane >> 4;
  const int d = (int)(blockIdx.x >> 7);
  const int bflat = (int)(blockIdx.x & 127);
  const int bg = bflat >> 6;
  const int cg = bflat & 63;
  const int n0 = cg << 4;
  const int r0 = bg * 32 + l15, r1 = r0 + 16;
  const int kw = w * 32 + l4 * 8;

  __threadfence();  // one-time: start from clean L1/L2 (poison lines dropped)

  // ---- step-invariant B fragments in registers ----
  short8 Bf[8][4];
#pragma unroll
  for (int jj = 0; jj < 8; ++jj) {
    int slab = w + jj * 8;
#pragma unroll
    for (int nt = 0; nt < 4; ++nt) {
      int row64 = nt * 16 + l15;
      size_t grow = (size_t)((d * 4 + (row64 >> 4)) * 1024 + n0 + (row64 & 15));
      Bf[jj][nt] = *(const short8*)(Wbf + grow * 2048 + slab * 32 + l4 * 8);
    }
  }

  const int b32 = tid >> 4, c16 = tid & 15;
  const int gcol = n0 + c16, gbrow = bg * 32 + b32;
  float brg[4];
#pragma unroll
  for (int g4 = 0; g4 < 4; ++g4) brg[g4] = biasws[d * 4096 + g4 * 1024 + gcol];
  float c_reg = 0.f;

  // ---- flags: u32 [d][bg][cg][wave]; monotone, no reset ----
  unsigned* const grpf = bar + (d * 2 + bg) * 512;
  unsigned* const fpub = grpf + cg * 8 + w;
  unsigned* const fpoll =
      grpf + ((lane >> 4) * 16 + 2 * w + ((lane >> 3) & 1)) * 8 + (lane & 7);

  const f32x4 fzero = {0.f, 0.f, 0.f, 0.f};
  f32x4 acc[2][4];

  auto X_PHASE = [&](int s) {
    const int td = d ? (T_SZ - 1 - s) : s;
    const short* xb0 = embT + (size_t)tokens[td * B_SZ + r0] * 1024 + kw;
    const short* xb1 = embT + (size_t)tokens[td * B_SZ + r1] * 1024 + kw;
    short8 xf[2][4];
#pragma unroll
    for (int jj = 0; jj < 4; ++jj) {
      xf[0][jj] = *(const short8*)(xb0 + jj * 256);
      xf[1][jj] = *(const short8*)(xb1 + jj * 256);
    }
#pragma unroll
    for (int ms = 0; ms < 2; ++ms)
#pragma unroll
      for (int nt = 0; nt < 4; ++nt) acc[ms][nt] = fzero;
#pragma unroll
    for (int jj = 0; jj < 4; ++jj)
#pragma unroll
      for (int ms = 0; ms < 2; ++ms)
#pragma unroll
        for (int nt = 0; nt < 4; ++nt)
          acc[ms][nt] = __builtin_amdgcn_mfma_f32_16x16x32_bf16(
              xf[ms][jj], Bf[jj][nt], acc[ms][nt], 0, 0, 0);
  };

  X_PHASE(0);

  for (int t = 0; t < T_SZ; ++t) {
    if (t > 0) {
      // ---- per-wave poll: my 8 producers' 8 wave-flags >= t ----
      const unsigned tgt = (unsigned)t;
      while (true) {
        unsigned v = __hip_atomic_load(fpoll, __ATOMIC_RELAXED,
                                       __HIP_MEMORY_SCOPE_AGENT);
        if (__all(v >= tgt)) break;
        __builtin_amdgcn_s_sleep(1);
      }
      short8 hf[2][4];
      if constexpr (CACHED) {
        // plain cached loads from write-once hseq[t][d]
        const short* hsrc = hseq + ((size_t)t * 2 + d) * 65536;
        const short* hb0 = hsrc + r0 * 1024 + kw;
        const short* hb1 = hsrc + r1 * 1024 + kw;
#pragma unroll
        for (int q = 0; q < 4; ++q) {
          hf[0][q] = *(const short8*)(hb0 + q * 256);
          hf[1][q] = *(const short8*)(hb1 + q * 256);
        }
      } else {
        const short* hsrc = hbf + ((t & 1) * 2 + d) * 65536;
        const short* hb0 = hsrc + r0 * 1024 + kw;
        const short* hb1 = hsrc + r1 * 1024 + kw;
        asm volatile(
            "global_load_dwordx4 %0, %8, off sc0 sc1\n\t"
            "global_load_dwordx4 %1, %8, off offset:512 sc0 sc1\n\t"
            "global_load_dwordx4 %2, %8, off offset:1024 sc0 sc1\n\t"
            "global_load_dwordx4 %3, %8, off offset:1536 sc0 sc1\n\t"
            "global_load_dwordx4 %4, %9, off sc0 sc1\n\t"
            "global_load_dwordx4 %5, %9, off offset:512 sc0 sc1\n\t"
            "global_load_dwordx4 %6, %9, off offset:1024 sc0 sc1\n\t"
            "global_load_dwordx4 %7, %9, off offset:1536 sc0 sc1\n\t"
            "s_waitcnt vmcnt(0)"
            : "=&v"(hf[0][0]), "=&v"(hf[0][1]), "=&v"(hf[0][2]), "=&v"(hf[0][3]),
              "=&v"(hf[1][0]), "=&v"(hf[1][1]), "=&v"(hf[1][2]), "=&v"(hf[1][3])
            : "v"(hb0), "v"(hb1)
            : "memory");
      }
#pragma unroll
      for (int q = 0; q < 4; ++q)
#pragma unroll
        for (int ms = 0; ms < 2; ++ms)
#pragma unroll
          for (int nt = 0; nt < 4; ++nt)
            acc[ms][nt] = __builtin_amdgcn_mfma_f32_16x16x32_bf16(
                hf[ms][q], Bf[4 + q][nt], acc[ms][nt], 0, 0, 0);
    }

    // ---- K-split partial dump into ping-pong buffer ----
#pragma unroll
    for (int ms = 0; ms < 2; ++ms)
#pragma unroll
      for (int nt = 0; nt < 4; ++nt)
#pragma unroll
        for (int i = 0; i < 4; ++i)
          P_lds[t & 1][w][ms * 16 + l4 * 4 + i][nt * 16 + l15] = acc[ms][nt][i];
    __syncthreads();  // S1 -- the ONLY barrier per step

    // ---- gate math + state update ----
    float pr[4];
#pragma unroll
    for (int g4 = 0; g4 < 4; ++g4) {
      float s = brg[g4];
#pragma unroll
      for (int q = 0; q < 8; ++q) s += P_lds[t & 1][q][b32][g4 * 16 + c16];
      pr[g4] = s;
    }
    float ig = fsig(pr[0]);
    float og = fsig(pr[1]);
    float fg = fsig(pr[2]);
    float cg4 = ftanh(pr[3]);
    c_reg = fg * c_reg + ig * cg4;
    float hnew = og * ftanh(c_reg);

    if (t < T_SZ - 1) {
      // ---- per-wave publish: pack 8 bf16 -> one 16B UC store per 8 lanes ----
      short* hdst = CACHED ? hseq + ((size_t)(t + 1) * 2 + d) * 65536
                           : hbf + (((t + 1) & 1) * 2 + d) * 65536;
      float s1 = __shfl_down(hnew, 1);
      unsigned ulo = cvtpk(hnew, s1);          // cols c, c+1
      unsigned uhi = __shfl_down(ulo, 2);      // cols c+2, c+3
      u64 pk = ((u64)uhi << 32) | (u64)ulo;    // cols c..c+3 (valid lane%4==0)
      u64 pk4 = __shfl_down(pk, 4);            // cols c+4..c+7 (valid lane%8==0)
      if ((lane & 7) == 0) {
        union { u64 q[2]; short8 s; } v16;
        v16.q[0] = pk; v16.q[1] = pk4;
        short* p = hdst + (size_t)gbrow * 1024 + n0 + (lane & 15);
        asm volatile("global_store_dwordx4 %0, %1, off sc0 sc1"
                     :: "v"(p), "v"(v16.s) : "memory");
      }
      asm volatile("s_waitcnt vmcnt(0)" ::: "memory");
      if (lane == 0)
        __hip_atomic_store(fpub, (unsigned)(t + 1), __ATOMIC_RELAXED,
                           __HIP_MEMORY_SCOPE_AGENT);
    }

    // out[] stores (plain cached, off critical path)
    size_t o = (size_t)(t * B_SZ + gbrow) * 2048 + (size_t)d * 1024 + gcol;
    out[o] = hnew;
    out[o + 67108864] = c_reg;

    if (t < T_SZ - 1) X_PHASE(t + 1);  // fills the poll shadow
  }
}

extern "C" void kernel_launch(void* const* d_in, const int* in_sizes, int n_in,
                              void* d_out, int out_size, void* d_ws, size_t ws_size,
                              hipStream_t stream) {
  (void)in_sizes; (void)n_in; (void)out_size;
  const int* tokens  = (const int*)d_in[0];
  const float* emb_w = (const float*)d_in[1];
  const float* emb_b = (const float*)d_in[2];

  char* ws = (char*)d_ws;
  short* embT   = (short*)(ws);               // 65,536,000 B
  short* Wbf    = (short*)(ws + 65536000);    // 33,554,432 B
  float* biasws = (float*)(ws + 99090432);    //     32,768 B
  short* hbf    = (short*)(ws + 99123200);    //    524,288 B (fallback 2-phase)
  unsigned* bar = (unsigned*)(ws + 99647488); //      8,192 B (per-wave flags)
  short* hseq   = (short*)(ws + 99655680);    // 134,217,728 B (write-once, cached path)
  const bool use_cached = ws_size >= (size_t)(99655680 + 134217728);

  (void)hipMemsetAsync(ws + 99123200, 0, 524288 + 8192, stream);

  k_embT<<<dim3(500, 16), 256, 0, stream>>>(emb_w, emb_b, embT);

  for (int d = 0; d < 2; ++d)
    for (int g = 0; g < 4; ++g) {
      const float* wsrc = (const float*)d_in[3 + d * 8 + g * 2];
      const float* bsrc = (const float*)d_in[4 + d * 8 + g * 2];
      k_cast<<<1024, 256, 0, stream>>>(wsrc, Wbf + (size_t)(d * 4 + g) * 1024 * 2048,
                                       1024 * 2048);
      k_copy<<<4, 256, 0, stream>>>(bsrc, biasws + (d * 4 + g) * 1024, 1024);
    }

  float* outp = (float*)d_out;
  void* kargs[] = {(void*)&tokens, (void*)&embT, (void*)&Wbf, (void*)&biasws,
                   (void*)&hbf, (void*)&hseq, (void*)&bar, (void*)&outp};
  if (use_cached)
    (void)hipLaunchCooperativeKernel((const void*)k_persist<true>, dim3(256),
                                     dim3(512), kargs, 0, stream);
  else
    (void)hipLaunchCooperativeKernel((const void*)k_persist<false>, dim3(256),
                                     dim3(512), kargs, 0, stream);
}

// Round 15
// 3117.131 us; speedup vs baseline: 1.2652x; 1.0377x over previous
//
#include <hip/hip_runtime.h>
#include <cstdint>
#include <cstddef>

#define V_SZ 32000
#define H_SZ 1024
#define T_SZ 512
#define B_SZ 64

typedef short short8 __attribute__((ext_vector_type(8)));
typedef float f32x4 __attribute__((ext_vector_type(4)));
typedef unsigned long long u64;

__device__ __forceinline__ short f2bf(float f) {
  union { float f; unsigned u; } v; v.f = f;
  unsigned r = (v.u + 0x7fffu + ((v.u >> 16) & 1u)) >> 16;  // RNE, inputs finite
  return (short)r;
}

__device__ __forceinline__ unsigned cvtpk(float a, float b) {  // lo=bf16(a), hi=bf16(b)
  unsigned r;
  asm("v_cvt_pk_bf16_f32 %0, %1, %2" : "=v"(r) : "v"(a), "v"(b));
  return r;
}

__device__ __forceinline__ float fsig(float x) {
  return __builtin_amdgcn_rcpf(1.f + __builtin_amdgcn_exp2f(x * -1.44269504f));
}
__device__ __forceinline__ float ftanh(float x) {
  return 1.f - 2.f * __builtin_amdgcn_rcpf(1.f + __builtin_amdgcn_exp2f(x * 2.88539008f));
}

__global__ __launch_bounds__(256) void k_embT(const float* __restrict__ emb_w,
                                              const float* __restrict__ emb_b,
                                              short* __restrict__ embT) {
  __shared__ float tile[64][65];
  const int v0 = blockIdx.x * 64, h0 = blockIdx.y * 64;
  const int c = threadIdx.x & 63, rg = threadIdx.x >> 6;
#pragma unroll
  for (int p = 0; p < 16; ++p) {
    int r = rg * 16 + p;
    tile[r][c] = emb_w[(size_t)(h0 + r) * V_SZ + v0 + c];
  }
  __syncthreads();
  const float bias = emb_b[h0 + c];
#pragma unroll
  for (int p = 0; p < 16; ++p) {
    int vr = rg * 16 + p;
    embT[(size_t)(v0 + vr) * H_SZ + h0 + c] = f2bf(tile[c][vr] + bias);
  }
}

__global__ __launch_bounds__(256) void k_cast(const float* __restrict__ s,
                                              short* __restrict__ d, int n) {
  for (int i = blockIdx.x * 256 + threadIdx.x; i < n; i += gridDim.x * 256)
    d[i] = f2bf(s[i]);
}

__global__ __launch_bounds__(256) void k_copy(const float* __restrict__ s,
                                              float* __restrict__ d, int n) {
  for (int i = blockIdx.x * 256 + threadIdx.x; i < n; i += gridDim.x * 256)
    d[i] = s[i];
}

// Persistent bidirectional LSTM. 256 blocks x 512 threads, 1 block/CU.
// XCD-PAIR DOMAINS: (d,bg) = bid&3, cg = bid>>2 -> each exchange domain's 64
// blocks sit on 2 XCDs (round-robin bid%8) => h/flag line requests come from
// 2 XCDs' queues, not 8 (perf heuristic only; correctness is mapping-free).
// wave w owns K-chunks {w*32 + jj*256} (4 x + 4 h). Weights Bf[8][4]=128 regs
// live in registers all 512 steps; c-state in register.
// SPLIT POLL/LOAD PIPELINE: poll low-32-lane producers (h slabs q=0,1) via
// ballot, load+MFMA those while q=2,3 producers finish, then full poll+rest.
// Per-wave 16B UC publish -> vmcnt(0) -> per-wave flag; single barrier per
// step via ping-pong P_lds. Safety chain (validated R12/R14): publish(t+1)
// is after S1(t), which joins all 8 waves' polls(t), whose producer-set
// union = all 64 blocks x 8 waves at flag >= t, each implying that block
// passed S1(t-1), i.e. all readers of the phase being overwritten are done.
__global__ __launch_bounds__(512, 2) void k_persist(
    const int* __restrict__ tokens, const short* __restrict__ embT,
    const short* __restrict__ Wbf, const float* __restrict__ biasws,
    short* __restrict__ hbf, unsigned* __restrict__ bar,
    float* __restrict__ out) {
  __shared__ float P_lds[2][8][32][68];  // ping-pong [K-eighth][b32][64+4 pad]

  const int tid = threadIdx.x;
  const int lane = tid & 63, w = tid >> 6;
  const int l15 = lane & 15, l4 = lane >> 4;
  const int bid = (int)blockIdx.x;
  const int m4 = bid & 3;
  const int d = m4 >> 1;                     // direction
  const int bg = m4 & 1;                     // batch half
  const int cg = bid >> 2;                   // col group 0..63
  const int n0 = cg << 4;
  const int r0 = bg * 32 + l15, r1 = r0 + 16;
  const int kw = w * 32 + l4 * 8;

  // ---- step-invariant B fragments in registers ----
  short8 Bf[8][4];
#pragma unroll
  for (int jj = 0; jj < 8; ++jj) {
    int slab = w + jj * 8;
#pragma unroll
    for (int nt = 0; nt < 4; ++nt) {
      int row64 = nt * 16 + l15;
      size_t grow = (size_t)((d * 4 + (row64 >> 4)) * 1024 + n0 + (row64 & 15));
      Bf[jj][nt] = *(const short8*)(Wbf + grow * 2048 + slab * 32 + l4 * 8);
    }
  }

  const int b32 = tid >> 4, c16 = tid & 15;
  const int gcol = n0 + c16, gbrow = bg * 32 + b32;
  float brg[4];
#pragma unroll
  for (int g4 = 0; g4 < 4; ++g4) brg[g4] = biasws[d * 4096 + g4 * 1024 + gcol];
  float c_reg = 0.f;

  // ---- flags: u32 [d][bg][cg][wave]; monotone, reset by host each call ----
  unsigned* const grpf = bar + (d * 2 + bg) * 512;
  unsigned* const fpub = grpf + cg * 8 + w;
  unsigned* const fpoll =
      grpf + ((lane >> 4) * 16 + 2 * w + ((lane >> 3) & 1)) * 8 + (lane & 7);

  const f32x4 fzero = {0.f, 0.f, 0.f, 0.f};
  f32x4 acc[2][4];

  auto X_PHASE = [&](int s) {
    const int td = d ? (T_SZ - 1 - s) : s;
    const short* xb0 = embT + (size_t)tokens[td * B_SZ + r0] * 1024 + kw;
    const short* xb1 = embT + (size_t)tokens[td * B_SZ + r1] * 1024 + kw;
    short8 xf[2][4];
#pragma unroll
    for (int jj = 0; jj < 4; ++jj) {
      xf[0][jj] = *(const short8*)(xb0 + jj * 256);
      xf[1][jj] = *(const short8*)(xb1 + jj * 256);
    }
#pragma unroll
    for (int ms = 0; ms < 2; ++ms)
#pragma unroll
      for (int nt = 0; nt < 4; ++nt) acc[ms][nt] = fzero;
#pragma unroll
    for (int jj = 0; jj < 4; ++jj)
#pragma unroll
      for (int ms = 0; ms < 2; ++ms)
#pragma unroll
        for (int nt = 0; nt < 4; ++nt)
          acc[ms][nt] = __builtin_amdgcn_mfma_f32_16x16x32_bf16(
              xf[ms][jj], Bf[jj][nt], acc[ms][nt], 0, 0, 0);
  };

  X_PHASE(0);

  for (int t = 0; t < T_SZ; ++t) {
    if (t > 0) {
      const unsigned tgt = (unsigned)t;
      const short* hsrc = hbf + ((t & 1) * 2 + d) * 65536;
      const short* hb0 = hsrc + r0 * 1024 + kw;
      const short* hb1 = hsrc + r1 * 1024 + kw;

      // ---- stage 1: poll producers of slabs q=0,1 (low 32 lanes) ----
      while (true) {
        unsigned v = __hip_atomic_load(fpoll, __ATOMIC_RELAXED,
                                       __HIP_MEMORY_SCOPE_AGENT);
        u64 rdy = __ballot(v >= tgt);
        if ((rdy & 0xFFFFFFFFull) == 0xFFFFFFFFull) break;
        __builtin_amdgcn_s_sleep(1);
      }
      short8 hf0[2][2];
      asm volatile(
          "global_load_dwordx4 %0, %4, off sc0 sc1\n\t"
          "global_load_dwordx4 %1, %4, off offset:512 sc0 sc1\n\t"
          "global_load_dwordx4 %2, %5, off sc0 sc1\n\t"
          "global_load_dwordx4 %3, %5, off offset:512 sc0 sc1\n\t"
          "s_waitcnt vmcnt(0)"
          : "=&v"(hf0[0][0]), "=&v"(hf0[0][1]), "=&v"(hf0[1][0]), "=&v"(hf0[1][1])
          : "v"(hb0), "v"(hb1)
          : "memory");
#pragma unroll
      for (int q = 0; q < 2; ++q)
#pragma unroll
        for (int ms = 0; ms < 2; ++ms)
#pragma unroll
          for (int nt = 0; nt < 4; ++nt)
            acc[ms][nt] = __builtin_amdgcn_mfma_f32_16x16x32_bf16(
                hf0[ms][q], Bf[4 + q][nt], acc[ms][nt], 0, 0, 0);

      // ---- stage 2: full poll, then slabs q=2,3 ----
      while (true) {
        unsigned v = __hip_atomic_load(fpoll, __ATOMIC_RELAXED,
                                       __HIP_MEMORY_SCOPE_AGENT);
        if (__all(v >= tgt)) break;
        __builtin_amdgcn_s_sleep(1);
      }
      short8 hf1[2][2];
      asm volatile(
          "global_load_dwordx4 %0, %4, off offset:1024 sc0 sc1\n\t"
          "global_load_dwordx4 %1, %4, off offset:1536 sc0 sc1\n\t"
          "global_load_dwordx4 %2, %5, off offset:1024 sc0 sc1\n\t"
          "global_load_dwordx4 %3, %5, off offset:1536 sc0 sc1\n\t"
          "s_waitcnt vmcnt(0)"
          : "=&v"(hf1[0][0]), "=&v"(hf1[0][1]), "=&v"(hf1[1][0]), "=&v"(hf1[1][1])
          : "v"(hb0), "v"(hb1)
          : "memory");
#pragma unroll
      for (int q = 0; q < 2; ++q)
#pragma unroll
        for (int ms = 0; ms < 2; ++ms)
#pragma unroll
          for (int nt = 0; nt < 4; ++nt)
            acc[ms][nt] = __builtin_amdgcn_mfma_f32_16x16x32_bf16(
                hf1[ms][q], Bf[6 + q][nt], acc[ms][nt], 0, 0, 0);
    }

    // ---- K-split partial dump into ping-pong buffer ----
#pragma unroll
    for (int ms = 0; ms < 2; ++ms)
#pragma unroll
      for (int nt = 0; nt < 4; ++nt)
#pragma unroll
        for (int i = 0; i < 4; ++i)
          P_lds[t & 1][w][ms * 16 + l4 * 4 + i][nt * 16 + l15] = acc[ms][nt][i];
    __syncthreads();  // S1 -- the only barrier per step

    // ---- gate math + state update ----
    float pr[4];
#pragma unroll
    for (int g4 = 0; g4 < 4; ++g4) {
      float s = brg[g4];
#pragma unroll
      for (int q = 0; q < 8; ++q) s += P_lds[t & 1][q][b32][g4 * 16 + c16];
      pr[g4] = s;
    }
    float ig = fsig(pr[0]);
    float og = fsig(pr[1]);
    float fg = fsig(pr[2]);
    float cg4 = ftanh(pr[3]);
    c_reg = fg * c_reg + ig * cg4;
    float hnew = og * ftanh(c_reg);

    if (t < T_SZ - 1) {
      // ---- per-wave publish: pack 8 bf16 -> one 16B UC store per 8 lanes ----
      short* hdst = hbf + (((t + 1) & 1) * 2 + d) * 65536;
      float s1 = __shfl_down(hnew, 1);
      unsigned ulo = cvtpk(hnew, s1);
      unsigned uhi = __shfl_down(ulo, 2);
      u64 pk = ((u64)uhi << 32) | (u64)ulo;
      u64 pk4 = __shfl_down(pk, 4);
      if ((lane & 7) == 0) {
        union { u64 q[2]; short8 s; } v16;
        v16.q[0] = pk; v16.q[1] = pk4;
        short* p = hdst + (size_t)gbrow * 1024 + n0 + (lane & 15);
        asm volatile("global_store_dwordx4 %0, %1, off sc0 sc1"
                     :: "v"(p), "v"(v16.s) : "memory");
      }
      asm volatile("s_waitcnt vmcnt(0)" ::: "memory");
      if (lane == 0)
        __hip_atomic_store(fpub, (unsigned)(t + 1), __ATOMIC_RELAXED,
                           __HIP_MEMORY_SCOPE_AGENT);
    }

    // out[] stores (plain cached, off critical path)
    size_t o = (size_t)(t * B_SZ + gbrow) * 2048 + (size_t)d * 1024 + gcol;
    out[o] = hnew;
    out[o + 67108864] = c_reg;

    if (t < T_SZ - 1) X_PHASE(t + 1);  // fills the poll shadow
  }
}

extern "C" void kernel_launch(void* const* d_in, const int* in_sizes, int n_in,
                              void* d_out, int out_size, void* d_ws, size_t ws_size,
                              hipStream_t stream) {
  (void)in_sizes; (void)n_in; (void)out_size; (void)ws_size;
  const int* tokens  = (const int*)d_in[0];
  const float* emb_w = (const float*)d_in[1];
  const float* emb_b = (const float*)d_in[2];

  char* ws = (char*)d_ws;
  short* embT   = (short*)(ws);               // 65,536,000 B
  short* Wbf    = (short*)(ws + 65536000);    // 33,554,432 B
  float* biasws = (float*)(ws + 99090432);    //     32,768 B
  short* hbf    = (short*)(ws + 99123200);    //    524,288 B (2-phase h)
  unsigned* bar = (unsigned*)(ws + 99647488); //      8,192 B (per-wave flags)

  // flags MUST be zeroed every call (monotone protocol; graph replays reuse ws)
  (void)hipMemsetAsync(ws + 99647488, 0, 8192, stream);

  k_embT<<<dim3(500, 16), 256, 0, stream>>>(emb_w, emb_b, embT);

  for (int d = 0; d < 2; ++d)
    for (int g = 0; g < 4; ++g) {
      const float* wsrc = (const float*)d_in[3 + d * 8 + g * 2];
      const float* bsrc = (const float*)d_in[4 + d * 8 + g * 2];
      k_cast<<<1024, 256, 0, stream>>>(wsrc, Wbf + (size_t)(d * 4 + g) * 1024 * 2048,
                                       1024 * 2048);
      k_copy<<<4, 256, 0, stream>>>(bsrc, biasws + (d * 4 + g) * 1024, 1024);
    }

  float* outp = (float*)d_out;
  void* kargs[] = {(void*)&tokens, (void*)&embT, (void*)&Wbf, (void*)&biasws,
                   (void*)&hbf, (void*)&bar, (void*)&outp};
  (void)hipLaunchCooperativeKernel((const void*)k_persist, dim3(256), dim3(512),
                                   kargs, 0, stream);
}